// Round 1
// baseline (265.619 us; speedup 1.0000x reference)
//
#include <hip/hip_runtime.h>

#define B_      8
#define CIN_    256
#define COUT_   256
#define K_      4
#define H_      128
#define W_      128
#define NPTS_   512

__global__ __launch_bounds__(256) void ple_point_kernel(
    const float* __restrict__ input,   // [B, CIN, H, W]
    const float* __restrict__ ax,      // [B, NPTS]
    const float* __restrict__ ay,      // [B, NPTS]
    const float* __restrict__ Wp,      // [COUT, CIN]
    const float* __restrict__ bp,      // [COUT]
    const float* __restrict__ Woff,    // [K, 2, CIN]
    const float* __restrict__ boff,    // [K, 2]
    const float* __restrict__ Ww,      // [K, CIN]
    const float* __restrict__ bw,      // [K]
    float* __restrict__ out)           // [B, NPTS, COUT]
{
    const int gid = blockIdx.x;            // b*NPTS + p
    const int b   = gid >> 9;               // / NPTS_
    const int tid = threadIdx.x;             // channel index (phase 1) / out channel (phase 4)

    __shared__ float xs[CIN_];               // point column, then reused for xacc
    __shared__ float dotv[12];               // 8 flow dots + 4 logit dots

    const int ix = (int)truncf(ax[gid]);
    const int iy = (int)truncf(ay[gid]);

    const float* __restrict__ chan = input + (size_t)b * (CIN_ * H_ * W_) + (size_t)tid * (H_ * W_);

    // ---- phase 1: load the point's input column ----
    const float xc = chan[iy * W_ + ix];
    xs[tid] = xc;
    __syncthreads();

    // ---- phase 2: 12 dot products (8 flows + 4 logits), 3 per wave ----
    const int wave = tid >> 6;
    const int lane = tid & 63;
    #pragma unroll
    for (int r = 0; r < 3; ++r) {
        const int d = wave * 3 + r;
        const float* __restrict__ row = (d < 8) ? (Woff + d * CIN_) : (Ww + (d - 8) * CIN_);
        float s = 0.f;
        #pragma unroll
        for (int q = 0; q < 4; ++q) {
            const int c = lane + q * 64;
            s = fmaf(xs[c], row[c], s);
        }
        #pragma unroll
        for (int off = 32; off > 0; off >>= 1)
            s += __shfl_down(s, off);
        if (lane == 0) dotv[d] = s;
    }
    __syncthreads();

    // ---- phase 3: softmax + bilinear corner weights (redundant per-thread, cheap) ----
    float lg[K_];
    float mx = -1e30f;
    #pragma unroll
    for (int k = 0; k < K_; ++k) {
        lg[k] = dotv[8 + k] + bw[k];
        mx = fmaxf(mx, lg[k]);
    }
    float se = 0.f;
    #pragma unroll
    for (int k = 0; k < K_; ++k) {
        lg[k] = expf(lg[k] - mx);
        se += lg[k];
    }
    const float inv_se = 1.f / se;

    const float scale = 128.0f / 127.0f;   // W/(W-1) == H/(H-1)

    float xacc = 0.f;   // weighted gather of this thread's channel
    float wsum = 0.f;   // sum of valid weights (identical across threads)

    #pragma unroll
    for (int k = 0; k < K_; ++k) {
        const float wk = lg[k] * inv_se;
        const float fx = dotv[2 * k]     + boff[2 * k];
        const float fy = dotv[2 * k + 1] + boff[2 * k + 1];
        const float sxv = ((float)ix + fx) * scale - 0.5f;
        const float syv = ((float)iy + fy) * scale - 0.5f;
        const float x0f = floorf(sxv);
        const float y0f = floorf(syv);
        const float wx1 = sxv - x0f;
        const float wy1 = syv - y0f;
        const int x0 = (int)x0f;
        const int y0 = (int)y0f;
        const int x1 = x0 + 1;
        const int y1 = y0 + 1;
        const float w00 = (1.f - wx1) * (1.f - wy1) * wk;
        const float w10 = wx1 * (1.f - wy1) * wk;
        const float w01 = (1.f - wx1) * wy1 * wk;
        const float w11 = wx1 * wy1 * wk;
        const bool vx0 = (x0 >= 0) && (x0 < W_);
        const bool vx1 = (x1 >= 0) && (x1 < W_);
        if (y0 >= 0 && y0 < H_) {
            const float* rowp = chan + y0 * W_;
            if (vx0) { xacc = fmaf(w00, rowp[x0], xacc); wsum += w00; }
            if (vx1) { xacc = fmaf(w10, rowp[x1], xacc); wsum += w10; }
        }
        if (y1 >= 0 && y1 < H_) {
            const float* rowp = chan + y1 * W_;
            if (vx0) { xacc = fmaf(w01, rowp[x0], xacc); wsum += w01; }
            if (vx1) { xacc = fmaf(w11, rowp[x1], xacc); wsum += w11; }
        }
    }

    // xs reads all happened before the last barrier; safe to overwrite, then barrier.
    xs[tid] = xacc;
    __syncthreads();

    // ---- phase 4: out[o] = Wp[o,:] @ xacc + bp[o] * wsum ----
    const float* __restrict__ wrow = Wp + tid * CIN_;
    float a0 = bp[tid] * wsum, a1 = 0.f, a2 = 0.f, a3 = 0.f;
    #pragma unroll 4
    for (int c = 0; c < CIN_; c += 4) {
        const float4 wv = *reinterpret_cast<const float4*>(wrow + c);
        a0 = fmaf(wv.x, xs[c],     a0);
        a1 = fmaf(wv.y, xs[c + 1], a1);
        a2 = fmaf(wv.z, xs[c + 2], a2);
        a3 = fmaf(wv.w, xs[c + 3], a3);
    }
    out[(size_t)gid * COUT_ + tid] = (a0 + a1) + (a2 + a3);
}

extern "C" void kernel_launch(void* const* d_in, const int* in_sizes, int n_in,
                              void* d_out, int out_size, void* d_ws, size_t ws_size,
                              hipStream_t stream) {
    const float* input = (const float*)d_in[0];
    const float* ax    = (const float*)d_in[1];
    const float* ay    = (const float*)d_in[2];
    const float* Wp    = (const float*)d_in[3];
    const float* bp    = (const float*)d_in[4];
    const float* Woff  = (const float*)d_in[5];
    const float* boff  = (const float*)d_in[6];
    const float* Ww    = (const float*)d_in[7];
    const float* bw    = (const float*)d_in[8];
    float* out = (float*)d_out;

    dim3 grid(B_ * NPTS_);
    dim3 block(256);
    ple_point_kernel<<<grid, block, 0, stream>>>(input, ax, ay, Wp, bp, Woff, boff, Ww, bw, out);
}

// Round 2
// 84.135 us; speedup vs baseline: 3.1571x; 3.1571x over previous
//
#include <hip/hip_runtime.h>
#include <hip/hip_fp16.h>

#define B_      8
#define CIN_    256
#define COUT_   256
#define K_      4
#define H_      128
#define W_      128
#define NPTS_   512

// =====================================================================
// K0: transpose input [B, C, H, W] fp32 -> T [B, H, W, C] fp16
// grid: B * H * (C/32) = 8 * 128 * 8 = 8192 blocks, 256 threads
// =====================================================================
__global__ __launch_bounds__(256) void transpose_hwc_kernel(
    const float* __restrict__ in, __half* __restrict__ T)
{
    const int blk = blockIdx.x;
    const int b   = blk >> 10;          // /1024
    const int r   = blk & 1023;
    const int h   = r >> 3;
    const int cb  = r & 7;
    const int c0  = cb << 5;            // *32

    __shared__ float lt[32][129];       // [c][w], pad to 129 (2-way banks max)

    const int t = threadIdx.x;
    const int c = t >> 3;               // 0..31
    const int m = t & 7;                // 0..7

    const float* __restrict__ src = in + (((size_t)(b * CIN_ + c0 + c) * H_ + h) * W_);
    #pragma unroll
    for (int q = 0; q < 4; ++q) {
        const int w = m * 4 + q * 32;
        const float4 v = *reinterpret_cast<const float4*>(src + w);
        lt[c][w]     = v.x;
        lt[c][w + 1] = v.y;
        lt[c][w + 2] = v.z;
        lt[c][w + 3] = v.w;
    }
    __syncthreads();

    // write: thread covers (w = t/2, 16 channels starting at (t&1)*16)
    const int w  = t >> 1;
    const int hc = (t & 1) << 4;
    unsigned int words[8];
    #pragma unroll
    for (int i = 0; i < 8; ++i) {
        __half2 h2 = __floats2half2_rn(lt[hc + 2 * i][w], lt[hc + 2 * i + 1][w]);
        words[i] = *reinterpret_cast<unsigned int*>(&h2);
    }
    __half* dst = T + (((size_t)(b * H_ + h) * W_ + w) * CIN_ + c0 + hc);
    uint4 u0 = make_uint4(words[0], words[1], words[2], words[3]);
    uint4 u1 = make_uint4(words[4], words[5], words[6], words[7]);
    reinterpret_cast<uint4*>(dst)[0] = u0;
    reinterpret_cast<uint4*>(dst)[1] = u1;
}

// =====================================================================
// K1: 8 points per block, 256 threads. Coalesced gathers from HWC fp16,
// LDS-staged Wp matvec amortized over the 8 points.
// grid: B*NPTS/8 = 512 blocks
// =====================================================================
__global__ __launch_bounds__(256) void ple_main_kernel(
    const __half* __restrict__ T,      // [B, H, W, C] fp16
    const float* __restrict__ ax,      // [B, NPTS]
    const float* __restrict__ ay,
    const float* __restrict__ Wp,      // [COUT, CIN]
    const float* __restrict__ bp,      // [COUT]
    const float* __restrict__ Woff,    // [K, 2, CIN]
    const float* __restrict__ boff,    // [K, 2]
    const float* __restrict__ Ww,      // [K, CIN]
    const float* __restrict__ bw,      // [K]
    float* __restrict__ out)           // [B*NPTS, COUT]
{
    const int blk = blockIdx.x;        // 0..511
    const int p0  = blk << 3;          // first point gid
    const int b   = p0 >> 9;           // / NPTS_
    const int tid = threadIdx.x;

    __shared__ float xsh[8][256];      // input columns, then gathered X
    __shared__ float dotv[8][12];
    __shared__ float wcor[8][16];      // combined (softmax x bilinear) weights, 0 if invalid
    __shared__ int   sbase[8][16];     // element base index in T (channel 0)
    __shared__ float wsums[8];
    __shared__ int   pix[8], piy[8];
    __shared__ float Wt[256 * 32];     // swizzled Wp tile [o][32]

    if (tid < 8) {
        const int gid = p0 + tid;
        pix[tid] = (int)truncf(ax[gid]);
        piy[tid] = (int)truncf(ay[gid]);
    }
    __syncthreads();

    // ---- phase 1: load 8 input columns (coalesced, 8 fp16 per thread) ----
    {
        const int p  = tid >> 5;             // 0..7
        const int cc = (tid & 31) << 3;      // 0..248
        const __half* col = T + (((size_t)(b * H_ + piy[p]) * W_ + pix[p]) * CIN_ + cc);
        union { uint4 u; __half h[8]; } raw;
        raw.u = *reinterpret_cast<const uint4*>(col);
        #pragma unroll
        for (int j = 0; j < 8; ++j) xsh[p][cc + j] = __half2float(raw.h[j]);
    }
    __syncthreads();

    // ---- phase 2: 96 dot products (8 points x 12), 24 per wave ----
    const int wave = tid >> 6;
    const int lane = tid & 63;
    for (int r = 0; r < 24; ++r) {
        const int idx = wave * 24 + r;       // 0..95
        const int p = idx / 12;
        const int d = idx % 12;
        const float* __restrict__ row = (d < 8) ? (Woff + d * CIN_) : (Ww + (d - 8) * CIN_);
        float s = 0.f;
        #pragma unroll
        for (int q = 0; q < 4; ++q) {
            const int c = lane + q * 64;
            s = fmaf(xsh[p][c], row[c], s);
        }
        #pragma unroll
        for (int off = 32; off > 0; off >>= 1)
            s += __shfl_down(s, off);
        if (lane == 0) dotv[p][d] = s;
    }
    __syncthreads();

    // ---- phase 3: 32 threads compute (p,k) site weights + addresses ----
    if (tid < 32) {
        const int p = tid >> 2, k = tid & 3;
        const float l0 = dotv[p][8]  + bw[0];
        const float l1 = dotv[p][9]  + bw[1];
        const float l2 = dotv[p][10] + bw[2];
        const float l3 = dotv[p][11] + bw[3];
        const float mx = fmaxf(fmaxf(l0, l1), fmaxf(l2, l3));
        const float e0 = expf(l0 - mx), e1 = expf(l1 - mx);
        const float e2 = expf(l2 - mx), e3 = expf(l3 - mx);
        const float ek = (k == 0) ? e0 : (k == 1) ? e1 : (k == 2) ? e2 : e3;
        const float wk = ek / (e0 + e1 + e2 + e3);

        const float scale = 128.0f / 127.0f;
        const float fx = dotv[p][2 * k]     + boff[2 * k];
        const float fy = dotv[p][2 * k + 1] + boff[2 * k + 1];
        const float sxv = ((float)pix[p] + fx) * scale - 0.5f;
        const float syv = ((float)piy[p] + fy) * scale - 0.5f;
        const float x0f = floorf(sxv), y0f = floorf(syv);
        const float wx1 = sxv - x0f, wy1 = syv - y0f;
        const int x0 = (int)x0f, y0 = (int)y0f;
        #pragma unroll
        for (int ci = 0; ci < 4; ++ci) {
            const int xi = x0 + (ci & 1);
            const int yi = y0 + (ci >> 1);
            const bool valid = (xi >= 0) & (xi < W_) & (yi >= 0) & (yi < H_);
            float wc = ((ci & 1) ? wx1 : 1.f - wx1) * ((ci >> 1) ? wy1 : 1.f - wy1) * wk;
            wc = valid ? wc : 0.f;
            const int xc = min(max(xi, 0), W_ - 1);
            const int yc = min(max(yi, 0), H_ - 1);
            wcor[p][k * 4 + ci]  = wc;
            sbase[p][k * 4 + ci] = ((b * H_ + yc) * W_ + xc) * CIN_;
        }
    }
    __syncthreads();

    if (tid < 8) {
        float s = 0.f;
        #pragma unroll
        for (int i = 0; i < 16; ++i) s += wcor[tid][i];
        wsums[tid] = s;   // published by the barrier after xsh overwrite below
    }

    // ---- phase 4: gather 16 sites per point (coalesced: lane = channel) ----
    float X[8];
    #pragma unroll
    for (int p = 0; p < 8; ++p) {
        float acc = 0.f;
        #pragma unroll
        for (int s = 0; s < 16; ++s) {
            const float wc = wcor[p][s];
            const __half v = T[(size_t)sbase[p][s] + tid];
            acc = fmaf(wc, __half2float(v), acc);
        }
        X[p] = acc;
    }
    // safe: all xsh readers crossed the phase-3 barrier
    #pragma unroll
    for (int p = 0; p < 8; ++p) xsh[p][tid] = X[p];
    __syncthreads();

    // ---- phase 5: out[p][o] = Wp[o,:] @ X[p] + bp[o]*wsum[p], staged tiles ----
    float acc[8];
    #pragma unroll
    for (int p = 0; p < 8; ++p) acc[p] = bp[tid] * wsums[p];

    const int m    = tid & 7;
    const int orow = tid >> 3;
    for (int ct = 0; ct < 8; ++ct) {
        // stage Wp[:, ct*32 .. +32) into LDS, XOR-swizzled column groups
        #pragma unroll
        for (int pass = 0; pass < 8; ++pass) {
            const int o = pass * 32 + orow;
            const float4 v = *reinterpret_cast<const float4*>(Wp + o * CIN_ + ct * 32 + m * 4);
            const int g = m ^ (o & 7);
            *reinterpret_cast<float4*>(&Wt[o * 32 + g * 4]) = v;
        }
        __syncthreads();
        #pragma unroll
        for (int gg = 0; gg < 8; ++gg) {
            const int g = gg ^ (tid & 7);
            const float4 wv = *reinterpret_cast<const float4*>(&Wt[tid * 32 + g * 4]);
            const int cbase = ct * 32 + gg * 4;
            #pragma unroll
            for (int p = 0; p < 8; ++p) {
                const float4 xv = *reinterpret_cast<const float4*>(&xsh[p][cbase]);
                acc[p] = fmaf(wv.x, xv.x, fmaf(wv.y, xv.y, fmaf(wv.z, xv.z, fmaf(wv.w, xv.w, acc[p]))));
            }
        }
        __syncthreads();
    }

    #pragma unroll
    for (int p = 0; p < 8; ++p)
        out[(size_t)(p0 + p) * COUT_ + tid] = acc[p];
}

// =====================================================================
// Fallback (round-1 kernel): used only if ws_size is too small.
// =====================================================================
__global__ __launch_bounds__(256) void ple_point_kernel(
    const float* __restrict__ input, const float* __restrict__ ax,
    const float* __restrict__ ay, const float* __restrict__ Wp,
    const float* __restrict__ bp, const float* __restrict__ Woff,
    const float* __restrict__ boff, const float* __restrict__ Ww,
    const float* __restrict__ bw, float* __restrict__ out)
{
    const int gid = blockIdx.x;
    const int b   = gid >> 9;
    const int tid = threadIdx.x;

    __shared__ float xs[CIN_];
    __shared__ float dotv[12];

    const int ix = (int)truncf(ax[gid]);
    const int iy = (int)truncf(ay[gid]);
    const float* __restrict__ chan = input + (size_t)b * (CIN_ * H_ * W_) + (size_t)tid * (H_ * W_);

    xs[tid] = chan[iy * W_ + ix];
    __syncthreads();

    const int wave = tid >> 6;
    const int lane = tid & 63;
    #pragma unroll
    for (int r = 0; r < 3; ++r) {
        const int d = wave * 3 + r;
        const float* __restrict__ row = (d < 8) ? (Woff + d * CIN_) : (Ww + (d - 8) * CIN_);
        float s = 0.f;
        #pragma unroll
        for (int q = 0; q < 4; ++q) s = fmaf(xs[lane + q * 64], row[lane + q * 64], s);
        #pragma unroll
        for (int off = 32; off > 0; off >>= 1) s += __shfl_down(s, off);
        if (lane == 0) dotv[d] = s;
    }
    __syncthreads();

    float lg[K_];
    float mx = -1e30f;
    #pragma unroll
    for (int k = 0; k < K_; ++k) { lg[k] = dotv[8 + k] + bw[k]; mx = fmaxf(mx, lg[k]); }
    float se = 0.f;
    #pragma unroll
    for (int k = 0; k < K_; ++k) { lg[k] = expf(lg[k] - mx); se += lg[k]; }
    const float inv_se = 1.f / se;
    const float scale = 128.0f / 127.0f;

    float xacc = 0.f, wsum = 0.f;
    #pragma unroll
    for (int k = 0; k < K_; ++k) {
        const float wk = lg[k] * inv_se;
        const float fx = dotv[2 * k] + boff[2 * k];
        const float fy = dotv[2 * k + 1] + boff[2 * k + 1];
        const float sxv = ((float)ix + fx) * scale - 0.5f;
        const float syv = ((float)iy + fy) * scale - 0.5f;
        const float x0f = floorf(sxv), y0f = floorf(syv);
        const float wx1 = sxv - x0f, wy1 = syv - y0f;
        const int x0 = (int)x0f, y0 = (int)y0f;
        const int x1 = x0 + 1, y1 = y0 + 1;
        const float w00 = (1.f - wx1) * (1.f - wy1) * wk;
        const float w10 = wx1 * (1.f - wy1) * wk;
        const float w01 = (1.f - wx1) * wy1 * wk;
        const float w11 = wx1 * wy1 * wk;
        const bool vx0 = (x0 >= 0) && (x0 < W_);
        const bool vx1 = (x1 >= 0) && (x1 < W_);
        if (y0 >= 0 && y0 < H_) {
            const float* rowp = chan + y0 * W_;
            if (vx0) { xacc = fmaf(w00, rowp[x0], xacc); wsum += w00; }
            if (vx1) { xacc = fmaf(w10, rowp[x1], xacc); wsum += w10; }
        }
        if (y1 >= 0 && y1 < H_) {
            const float* rowp = chan + y1 * W_;
            if (vx0) { xacc = fmaf(w01, rowp[x0], xacc); wsum += w01; }
            if (vx1) { xacc = fmaf(w11, rowp[x1], xacc); wsum += w11; }
        }
    }

    xs[tid] = xacc;
    __syncthreads();

    const float* __restrict__ wrow = Wp + tid * CIN_;
    float a0 = bp[tid] * wsum, a1 = 0.f, a2 = 0.f, a3 = 0.f;
    #pragma unroll 4
    for (int c = 0; c < CIN_; c += 4) {
        const float4 wv = *reinterpret_cast<const float4*>(wrow + c);
        a0 = fmaf(wv.x, xs[c], a0);
        a1 = fmaf(wv.y, xs[c + 1], a1);
        a2 = fmaf(wv.z, xs[c + 2], a2);
        a3 = fmaf(wv.w, xs[c + 3], a3);
    }
    out[(size_t)gid * COUT_ + tid] = (a0 + a1) + (a2 + a3);
}

extern "C" void kernel_launch(void* const* d_in, const int* in_sizes, int n_in,
                              void* d_out, int out_size, void* d_ws, size_t ws_size,
                              hipStream_t stream) {
    const float* input = (const float*)d_in[0];
    const float* ax    = (const float*)d_in[1];
    const float* ay    = (const float*)d_in[2];
    const float* Wp    = (const float*)d_in[3];
    const float* bp    = (const float*)d_in[4];
    const float* Woff  = (const float*)d_in[5];
    const float* boff  = (const float*)d_in[6];
    const float* Ww    = (const float*)d_in[7];
    const float* bw    = (const float*)d_in[8];
    float* out = (float*)d_out;

    const size_t need = (size_t)B_ * H_ * W_ * CIN_ * sizeof(__half);  // 67.1 MB
    if (ws_size >= need) {
        __half* T = (__half*)d_ws;
        transpose_hwc_kernel<<<dim3(B_ * H_ * (CIN_ / 32)), dim3(256), 0, stream>>>(input, T);
        ple_main_kernel<<<dim3(B_ * NPTS_ / 8), dim3(256), 0, stream>>>(
            T, ax, ay, Wp, bp, Woff, boff, Ww, bw, out);
    } else {
        ple_point_kernel<<<dim3(B_ * NPTS_), dim3(256), 0, stream>>>(
            input, ax, ay, Wp, bp, Woff, boff, Ww, bw, out);
    }
}

// Round 3
// 73.044 us; speedup vs baseline: 3.6364x; 1.1518x over previous
//
#include <hip/hip_runtime.h>
#include <hip/hip_fp16.h>

#define B_      8
#define CIN_    256
#define COUT_   256
#define K_      4
#define H_      128
#define W_      128
#define NPTS_   512

#define NPTS_TOT_   (B_ * NPTS_)                 // 4096
#define T_BYTES_    ((size_t)B_ * H_ * W_ * CIN_ * sizeof(__half))   // 67,108,864
#define WTS_OFF_    T_BYTES_
#define SITES_OFF_  (WTS_OFF_   + (size_t)NPTS_TOT_ * 16 * 4)
#define WSUM_OFF_   (SITES_OFF_ + (size_t)NPTS_TOT_ * 16 * 4)
#define WS_NEED_    (WSUM_OFF_  + (size_t)NPTS_TOT_ * 4)

// =====================================================================
// K_A: fused. blocks [0,8192): transpose CHW fp32 -> HWC fp16.
//             blocks [8192,12288): per-point prep (column gather from CHW,
//             12 dots, softmax, flows, 16 (weight,site) pairs + wsum).
// =====================================================================
__global__ __launch_bounds__(256) void ka_kernel(
    const float* __restrict__ input,   // [B, CIN, H, W]
    const float* __restrict__ ax,      // [B, NPTS]
    const float* __restrict__ ay,
    const float* __restrict__ Woff,    // [K, 2, CIN]
    const float* __restrict__ boff,    // [K, 2]
    const float* __restrict__ Ww,      // [K, CIN]
    const float* __restrict__ bw,      // [K]
    __half* __restrict__ T,            // [B, H, W, C]
    float* __restrict__ wts_g,         // [4096][16]
    int*   __restrict__ sites_g,       // [4096][16]
    float* __restrict__ wsums_g)       // [4096]
{
    __shared__ float lt[32][129];      // transpose tile
    __shared__ float xs[CIN_];         // prep column
    __shared__ float dotv[12];
    __shared__ float wc16[16];

    const int bid = blockIdx.x;
    const int t   = threadIdx.x;

    if (bid < 8192) {
        // ---------------- transpose path ----------------
        const int b   = bid >> 10;
        const int r   = bid & 1023;
        const int h   = r >> 3;
        const int c0  = (r & 7) << 5;

        const int c = t >> 3;          // 0..31
        const int m = t & 7;           // 0..7
        const float* __restrict__ src = input + (((size_t)(b * CIN_ + c0 + c) * H_ + h) * W_);
        #pragma unroll
        for (int q = 0; q < 4; ++q) {
            const int w = m * 4 + q * 32;
            const float4 v = *reinterpret_cast<const float4*>(src + w);
            lt[c][w]     = v.x;
            lt[c][w + 1] = v.y;
            lt[c][w + 2] = v.z;
            lt[c][w + 3] = v.w;
        }
        __syncthreads();

        const int w  = t >> 1;
        const int hc = (t & 1) << 4;
        unsigned int words[8];
        #pragma unroll
        for (int i = 0; i < 8; ++i) {
            __half2 h2 = __floats2half2_rn(lt[hc + 2 * i][w], lt[hc + 2 * i + 1][w]);
            words[i] = *reinterpret_cast<unsigned int*>(&h2);
        }
        __half* dst = T + (((size_t)(b * H_ + h) * W_ + w) * CIN_ + c0 + hc);
        reinterpret_cast<uint4*>(dst)[0] = make_uint4(words[0], words[1], words[2], words[3]);
        reinterpret_cast<uint4*>(dst)[1] = make_uint4(words[4], words[5], words[6], words[7]);
        return;
    }

    // ---------------- prep path: one point per block ----------------
    const int pt = bid - 8192;          // 0..4095
    const int b  = pt >> 9;             // / NPTS_

    const int ix = (int)truncf(ax[pt]);
    const int iy = (int)truncf(ay[pt]);
    const float* __restrict__ chan = input + (size_t)b * (CIN_ * H_ * W_) + (size_t)t * (H_ * W_);

    xs[t] = chan[iy * W_ + ix];
    __syncthreads();

    const int wave = t >> 6;
    const int lane = t & 63;
    #pragma unroll
    for (int r = 0; r < 3; ++r) {
        const int d = wave * 3 + r;
        const float* __restrict__ row = (d < 8) ? (Woff + d * CIN_) : (Ww + (d - 8) * CIN_);
        float s = 0.f;
        #pragma unroll
        for (int q = 0; q < 4; ++q) {
            const int c = lane + q * 64;
            s = fmaf(xs[c], row[c], s);
        }
        #pragma unroll
        for (int off = 32; off > 0; off >>= 1)
            s += __shfl_down(s, off);
        if (lane == 0) dotv[d] = s;
    }
    __syncthreads();

    if (t < 4) {
        const int k = t;
        const float l0 = dotv[8]  + bw[0];
        const float l1 = dotv[9]  + bw[1];
        const float l2 = dotv[10] + bw[2];
        const float l3 = dotv[11] + bw[3];
        const float mx = fmaxf(fmaxf(l0, l1), fmaxf(l2, l3));
        const float e0 = expf(l0 - mx), e1 = expf(l1 - mx);
        const float e2 = expf(l2 - mx), e3 = expf(l3 - mx);
        const float ek = (k == 0) ? e0 : (k == 1) ? e1 : (k == 2) ? e2 : e3;
        const float wk = ek / (e0 + e1 + e2 + e3);

        const float scale = 128.0f / 127.0f;
        const float fx = dotv[2 * k]     + boff[2 * k];
        const float fy = dotv[2 * k + 1] + boff[2 * k + 1];
        const float sxv = ((float)ix + fx) * scale - 0.5f;
        const float syv = ((float)iy + fy) * scale - 0.5f;
        const float x0f = floorf(sxv), y0f = floorf(syv);
        const float wx1 = sxv - x0f, wy1 = syv - y0f;
        const int x0 = (int)x0f, y0 = (int)y0f;
        #pragma unroll
        for (int ci = 0; ci < 4; ++ci) {
            const int xi = x0 + (ci & 1);
            const int yi = y0 + (ci >> 1);
            const bool valid = (xi >= 0) & (xi < W_) & (yi >= 0) & (yi < H_);
            float wc = ((ci & 1) ? wx1 : 1.f - wx1) * ((ci >> 1) ? wy1 : 1.f - wy1) * wk;
            wc = valid ? wc : 0.f;
            const int xc = min(max(xi, 0), W_ - 1);
            const int yc = min(max(yi, 0), H_ - 1);
            const int idx = k * 4 + ci;
            wc16[idx] = wc;
            wts_g[pt * 16 + idx]   = wc;
            sites_g[pt * 16 + idx] = ((b * H_ + yc) * W_ + xc) * CIN_;
        }
    }
    __syncthreads();
    if (t == 0) {
        float s = 0.f;
        #pragma unroll
        for (int i = 0; i < 16; ++i) s += wc16[i];
        wsums_g[pt] = s;
    }
}

// =====================================================================
// K_B: 16 points per block, 512 threads (8 waves), 256 blocks.
// Coalesced corner gather from HWC fp16 T, then register-blocked matvec
// out[p][o] = Wp[o,:]@X[p] + bp[o]*wsum[p].
// =====================================================================
__global__ __launch_bounds__(512) void kb_kernel(
    const __half* __restrict__ T,
    const float* __restrict__ Wp,      // [COUT, CIN] fp32
    const float* __restrict__ bp,      // [COUT]
    const float* __restrict__ wts_g,   // [4096][16]
    const int*   __restrict__ sites_g, // [4096][16]
    const float* __restrict__ wsums_g, // [4096]
    float* __restrict__ out)           // [4096, COUT]
{
    __shared__ float xsh[16][260];         // gathered X, padded rows
    __shared__ float wtile[32 * 256];      // Wp chunk [c][o-swizzled], 32 KB
    __shared__ float swts[16][16];
    __shared__ int   ssites[16][16];
    __shared__ float swsum[16];

    const int blk = blockIdx.x;            // 0..255
    const int p0g = blk << 4;              // first global point
    const int tid = threadIdx.x;

    // ---- meta load ----
    if (tid < 256) {
        swts[tid >> 4][tid & 15]   = wts_g[p0g * 16 + tid];
        ssites[tid >> 4][tid & 15] = sites_g[p0g * 16 + tid];
    } else if (tid < 256 + 16) {
        swsum[tid - 256] = wsums_g[p0g + (tid - 256)];
    }
    __syncthreads();

    // ---- gather: thread owns (point p, channel octet oct) ----
    {
        const int p   = tid >> 5;          // 0..15
        const int oct = tid & 31;          // 0..31
        const int c0  = oct << 3;
        float a[8] = {0.f, 0.f, 0.f, 0.f, 0.f, 0.f, 0.f, 0.f};
        #pragma unroll
        for (int s = 0; s < 16; ++s) {
            const float w = swts[p][s];
            const uint4 raw = *reinterpret_cast<const uint4*>(T + (size_t)ssites[p][s] + c0);
            const __half* hh = reinterpret_cast<const __half*>(&raw);
            #pragma unroll
            for (int j = 0; j < 8; ++j)
                a[j] = fmaf(w, __half2float(hh[j]), a[j]);
        }
        *reinterpret_cast<float4*>(&xsh[p][c0])     = make_float4(a[0], a[1], a[2], a[3]);
        *reinterpret_cast<float4*>(&xsh[p][c0 + 4]) = make_float4(a[4], a[5], a[6], a[7]);
    }
    __syncthreads();

    // ---- matvec: thread owns 2 points x 4 outputs ----
    const int oq = tid & 63;               // o0 = oq*4
    const int pp = tid >> 6;               // wave id; p0 = pp*2
    const int o0 = oq << 2;
    const int p0 = pp << 1;

    const float4 bpv = *reinterpret_cast<const float4*>(bp + o0);
    const float ws0 = swsum[p0], ws1 = swsum[p0 + 1];
    float a00 = bpv.x * ws0, a01 = bpv.y * ws0, a02 = bpv.z * ws0, a03 = bpv.w * ws0;
    float a10 = bpv.x * ws1, a11 = bpv.y * ws1, a12 = bpv.z * ws1, a13 = bpv.w * ws1;

    for (int ch = 0; ch < 8; ++ch) {
        // stage Wp[:, ch*32..+32) -> wtile[c][o] with o-quad XOR swizzle
        #pragma unroll
        for (int r = 0; r < 4; ++r) {
            const int idx = r * 512 + tid;     // 0..2047
            const int c4  = idx & 7;           // c-quad within chunk
            const int o   = idx >> 3;          // 0..255
            const float4 v = *reinterpret_cast<const float4*>(Wp + (size_t)o * CIN_ + ch * 32 + c4 * 4);
            const float vv[4] = {v.x, v.y, v.z, v.w};
            #pragma unroll
            for (int m = 0; m < 4; ++m) {
                const int c  = c4 * 4 + m;
                const int os = (o >> 2) ^ (c & 7);         // swizzled o-quad
                wtile[c * 256 + (os << 2) + (o & 3)] = vv[m];
            }
        }
        __syncthreads();

        const int cb = ch * 32;
        #pragma unroll
        for (int cq = 0; cq < 8; ++cq) {
            const float4 x0 = *reinterpret_cast<const float4*>(&xsh[p0][cb + (cq << 2)]);
            const float4 x1 = *reinterpret_cast<const float4*>(&xsh[p0 + 1][cb + (cq << 2)]);
            const float x0a[4] = {x0.x, x0.y, x0.z, x0.w};
            const float x1a[4] = {x1.x, x1.y, x1.z, x1.w};
            #pragma unroll
            for (int m = 0; m < 4; ++m) {
                const int c = (cq << 2) + m;
                const float4 wv = *reinterpret_cast<const float4*>(
                    &wtile[c * 256 + ((oq ^ (c & 7)) << 2)]);
                const float xm0 = x0a[m], xm1 = x1a[m];
                a00 = fmaf(xm0, wv.x, a00); a01 = fmaf(xm0, wv.y, a01);
                a02 = fmaf(xm0, wv.z, a02); a03 = fmaf(xm0, wv.w, a03);
                a10 = fmaf(xm1, wv.x, a10); a11 = fmaf(xm1, wv.y, a11);
                a12 = fmaf(xm1, wv.z, a12); a13 = fmaf(xm1, wv.w, a13);
            }
        }
        __syncthreads();
    }

    float* o_row0 = out + (size_t)(p0g + p0) * COUT_ + o0;
    float* o_row1 = out + (size_t)(p0g + p0 + 1) * COUT_ + o0;
    *reinterpret_cast<float4*>(o_row0) = make_float4(a00, a01, a02, a03);
    *reinterpret_cast<float4*>(o_row1) = make_float4(a10, a11, a12, a13);
}

// =====================================================================
// Fallback (round-1 kernel): used only if ws_size is too small.
// =====================================================================
__global__ __launch_bounds__(256) void ple_point_kernel(
    const float* __restrict__ input, const float* __restrict__ ax,
    const float* __restrict__ ay, const float* __restrict__ Wp,
    const float* __restrict__ bp, const float* __restrict__ Woff,
    const float* __restrict__ boff, const float* __restrict__ Ww,
    const float* __restrict__ bw, float* __restrict__ out)
{
    const int gid = blockIdx.x;
    const int b   = gid >> 9;
    const int tid = threadIdx.x;

    __shared__ float xs[CIN_];
    __shared__ float dotv[12];

    const int ix = (int)truncf(ax[gid]);
    const int iy = (int)truncf(ay[gid]);
    const float* __restrict__ chan = input + (size_t)b * (CIN_ * H_ * W_) + (size_t)tid * (H_ * W_);

    xs[tid] = chan[iy * W_ + ix];
    __syncthreads();

    const int wave = tid >> 6;
    const int lane = tid & 63;
    #pragma unroll
    for (int r = 0; r < 3; ++r) {
        const int d = wave * 3 + r;
        const float* __restrict__ row = (d < 8) ? (Woff + d * CIN_) : (Ww + (d - 8) * CIN_);
        float s = 0.f;
        #pragma unroll
        for (int q = 0; q < 4; ++q) s = fmaf(xs[lane + q * 64], row[lane + q * 64], s);
        #pragma unroll
        for (int off = 32; off > 0; off >>= 1) s += __shfl_down(s, off);
        if (lane == 0) dotv[d] = s;
    }
    __syncthreads();

    float lg[K_];
    float mx = -1e30f;
    #pragma unroll
    for (int k = 0; k < K_; ++k) { lg[k] = dotv[8 + k] + bw[k]; mx = fmaxf(mx, lg[k]); }
    float se = 0.f;
    #pragma unroll
    for (int k = 0; k < K_; ++k) { lg[k] = expf(lg[k] - mx); se += lg[k]; }
    const float inv_se = 1.f / se;
    const float scale = 128.0f / 127.0f;

    float xacc = 0.f, wsum = 0.f;
    #pragma unroll
    for (int k = 0; k < K_; ++k) {
        const float wk = lg[k] * inv_se;
        const float fx = dotv[2 * k] + boff[2 * k];
        const float fy = dotv[2 * k + 1] + boff[2 * k + 1];
        const float sxv = ((float)ix + fx) * scale - 0.5f;
        const float syv = ((float)iy + fy) * scale - 0.5f;
        const float x0f = floorf(sxv), y0f = floorf(syv);
        const float wx1 = sxv - x0f, wy1 = syv - y0f;
        const int x0 = (int)x0f, y0 = (int)y0f;
        const int x1 = x0 + 1, y1 = y0 + 1;
        const float w00 = (1.f - wx1) * (1.f - wy1) * wk;
        const float w10 = wx1 * (1.f - wy1) * wk;
        const float w01 = (1.f - wx1) * wy1 * wk;
        const float w11 = wx1 * wy1 * wk;
        const bool vx0 = (x0 >= 0) && (x0 < W_);
        const bool vx1 = (x1 >= 0) && (x1 < W_);
        if (y0 >= 0 && y0 < H_) {
            const float* rowp = chan + y0 * W_;
            if (vx0) { xacc = fmaf(w00, rowp[x0], xacc); wsum += w00; }
            if (vx1) { xacc = fmaf(w10, rowp[x1], xacc); wsum += w10; }
        }
        if (y1 >= 0 && y1 < H_) {
            const float* rowp = chan + y1 * W_;
            if (vx0) { xacc = fmaf(w01, rowp[x0], xacc); wsum += w01; }
            if (vx1) { xacc = fmaf(w11, rowp[x1], xacc); wsum += w11; }
        }
    }

    xs[tid] = xacc;
    __syncthreads();

    const float* __restrict__ wrow = Wp + tid * CIN_;
    float a0 = bp[tid] * wsum, a1 = 0.f, a2 = 0.f, a3 = 0.f;
    #pragma unroll 4
    for (int c = 0; c < CIN_; c += 4) {
        const float4 wv = *reinterpret_cast<const float4*>(wrow + c);
        a0 = fmaf(wv.x, xs[c], a0);
        a1 = fmaf(wv.y, xs[c + 1], a1);
        a2 = fmaf(wv.z, xs[c + 2], a2);
        a3 = fmaf(wv.w, xs[c + 3], a3);
    }
    out[(size_t)gid * COUT_ + tid] = (a0 + a1) + (a2 + a3);
}

extern "C" void kernel_launch(void* const* d_in, const int* in_sizes, int n_in,
                              void* d_out, int out_size, void* d_ws, size_t ws_size,
                              hipStream_t stream) {
    const float* input = (const float*)d_in[0];
    const float* ax    = (const float*)d_in[1];
    const float* ay    = (const float*)d_in[2];
    const float* Wp    = (const float*)d_in[3];
    const float* bp    = (const float*)d_in[4];
    const float* Woff  = (const float*)d_in[5];
    const float* boff  = (const float*)d_in[6];
    const float* Ww    = (const float*)d_in[7];
    const float* bw    = (const float*)d_in[8];
    float* out = (float*)d_out;

    if (ws_size >= WS_NEED_) {
        __half* T      = (__half*)d_ws;
        float*  wts_g  = (float*)((char*)d_ws + WTS_OFF_);
        int*    sites_g= (int*)  ((char*)d_ws + SITES_OFF_);
        float*  wsums_g= (float*)((char*)d_ws + WSUM_OFF_);

        ka_kernel<<<dim3(8192 + NPTS_TOT_), dim3(256), 0, stream>>>(
            input, ax, ay, Woff, boff, Ww, bw, T, wts_g, sites_g, wsums_g);
        kb_kernel<<<dim3(256), dim3(512), 0, stream>>>(
            T, Wp, bp, wts_g, sites_g, wsums_g, out);
    } else {
        ple_point_kernel<<<dim3(B_ * NPTS_), dim3(256), 0, stream>>>(
            input, ax, ay, Wp, bp, Woff, boff, Ww, bw, out);
    }
}

// Round 4
// 72.263 us; speedup vs baseline: 3.6757x; 1.0108x over previous
//
#include <hip/hip_runtime.h>
#include <hip/hip_fp16.h>

#define B_      8
#define CIN_    256
#define COUT_   256
#define K_      4
#define H_      128
#define W_      128
#define NPTS_   512

#define NPTS_TOT_   (B_ * NPTS_)                 // 4096
#define T_BYTES_    ((size_t)B_ * H_ * W_ * CIN_ * sizeof(__half))   // 67,108,864
#define WTS_OFF_    T_BYTES_
#define SITES_OFF_  (WTS_OFF_   + (size_t)NPTS_TOT_ * 16 * 4)
#define WSUM_OFF_   (SITES_OFF_ + (size_t)NPTS_TOT_ * 16 * 4)
#define WS_NEED_    (WSUM_OFF_  + (size_t)NPTS_TOT_ * 4)

// =====================================================================
// K_A: fused. blocks [0,8192): transpose CHW fp32 -> HWC fp16.
//             blocks [8192,12288): per-point prep.
// Write phase of the transpose is granule-complete: lanes 4w..4w+3 fill
// one full 64-B granule of pixel w in a single store instruction.
// =====================================================================
__global__ __launch_bounds__(256) void ka_kernel(
    const float* __restrict__ input,   // [B, CIN, H, W]
    const float* __restrict__ ax,      // [B, NPTS]
    const float* __restrict__ ay,
    const float* __restrict__ Woff,    // [K, 2, CIN]
    const float* __restrict__ boff,    // [K, 2]
    const float* __restrict__ Ww,      // [K, CIN]
    const float* __restrict__ bw,      // [K]
    __half* __restrict__ T,            // [B, H, W, C]
    float* __restrict__ wts_g,         // [4096][16]
    int*   __restrict__ sites_g,       // [4096][16]
    float* __restrict__ wsums_g)       // [4096]
{
    __shared__ float lt[32][129];      // transpose tile
    __shared__ float xs[CIN_];         // prep column
    __shared__ float dotv[12];
    __shared__ float wc16[16];

    const int bid = blockIdx.x;
    const int t   = threadIdx.x;

    if (bid < 8192) {
        // ---------------- transpose path ----------------
        const int b   = bid >> 10;
        const int r   = bid & 1023;
        const int h   = r >> 3;
        const int c0  = (r & 7) << 5;

        const int c = t >> 3;          // 0..31
        const int m = t & 7;           // 0..7
        const float* __restrict__ src = input + (((size_t)(b * CIN_ + c0 + c) * H_ + h) * W_);
        #pragma unroll
        for (int q = 0; q < 4; ++q) {
            const int w = m * 4 + q * 32;
            const float4 v = *reinterpret_cast<const float4*>(src + w);
            lt[c][w]     = v.x;
            lt[c][w + 1] = v.y;
            lt[c][w + 2] = v.z;
            lt[c][w + 3] = v.w;
        }
        __syncthreads();

        // write: lane t -> pixel w=(t>>2)+64g, local channels (t&3)*8..+7.
        // Lanes 4w..4w+3 write one complete 64-B granule per instruction.
        const int wph = t >> 2;              // 0..63
        const int j0  = (t & 3) << 3;        // 0,8,16,24
        #pragma unroll
        for (int g = 0; g < 2; ++g) {
            const int w = wph + (g << 6);
            unsigned int words[4];
            #pragma unroll
            for (int i = 0; i < 4; ++i) {
                __half2 h2 = __floats2half2_rn(lt[j0 + 2 * i][w], lt[j0 + 2 * i + 1][w]);
                words[i] = *reinterpret_cast<unsigned int*>(&h2);
            }
            __half* dst = T + (((size_t)(b * H_ + h) * W_ + w) * CIN_ + c0 + j0);
            *reinterpret_cast<uint4*>(dst) = make_uint4(words[0], words[1], words[2], words[3]);
        }
        return;
    }

    // ---------------- prep path: one point per block ----------------
    const int pt = bid - 8192;          // 0..4095
    const int b  = pt >> 9;             // / NPTS_

    const int ix = (int)truncf(ax[pt]);
    const int iy = (int)truncf(ay[pt]);
    const float* __restrict__ chan = input + (size_t)b * (CIN_ * H_ * W_) + (size_t)t * (H_ * W_);

    xs[t] = chan[iy * W_ + ix];
    __syncthreads();

    const int wave = t >> 6;
    const int lane = t & 63;
    #pragma unroll
    for (int r = 0; r < 3; ++r) {
        const int d = wave * 3 + r;
        const float* __restrict__ row = (d < 8) ? (Woff + d * CIN_) : (Ww + (d - 8) * CIN_);
        float s = 0.f;
        #pragma unroll
        for (int q = 0; q < 4; ++q) {
            const int c = lane + q * 64;
            s = fmaf(xs[c], row[c], s);
        }
        #pragma unroll
        for (int off = 32; off > 0; off >>= 1)
            s += __shfl_down(s, off);
        if (lane == 0) dotv[d] = s;
    }
    __syncthreads();

    if (t < 4) {
        const int k = t;
        const float l0 = dotv[8]  + bw[0];
        const float l1 = dotv[9]  + bw[1];
        const float l2 = dotv[10] + bw[2];
        const float l3 = dotv[11] + bw[3];
        const float mx = fmaxf(fmaxf(l0, l1), fmaxf(l2, l3));
        const float e0 = expf(l0 - mx), e1 = expf(l1 - mx);
        const float e2 = expf(l2 - mx), e3 = expf(l3 - mx);
        const float ek = (k == 0) ? e0 : (k == 1) ? e1 : (k == 2) ? e2 : e3;
        const float wk = ek / (e0 + e1 + e2 + e3);

        const float scale = 128.0f / 127.0f;
        const float fx = dotv[2 * k]     + boff[2 * k];
        const float fy = dotv[2 * k + 1] + boff[2 * k + 1];
        const float sxv = ((float)ix + fx) * scale - 0.5f;
        const float syv = ((float)iy + fy) * scale - 0.5f;
        const float x0f = floorf(sxv), y0f = floorf(syv);
        const float wx1 = sxv - x0f, wy1 = syv - y0f;
        const int x0 = (int)x0f, y0 = (int)y0f;
        #pragma unroll
        for (int ci = 0; ci < 4; ++ci) {
            const int xi = x0 + (ci & 1);
            const int yi = y0 + (ci >> 1);
            const bool valid = (xi >= 0) & (xi < W_) & (yi >= 0) & (yi < H_);
            float wc = ((ci & 1) ? wx1 : 1.f - wx1) * ((ci >> 1) ? wy1 : 1.f - wy1) * wk;
            wc = valid ? wc : 0.f;
            const int xc = min(max(xi, 0), W_ - 1);
            const int yc = min(max(yi, 0), H_ - 1);
            const int idx = k * 4 + ci;
            wc16[idx] = wc;
            wts_g[pt * 16 + idx]   = wc;
            sites_g[pt * 16 + idx] = ((b * H_ + yc) * W_ + xc) * CIN_;
        }
    }
    __syncthreads();
    if (t == 0) {
        float s = 0.f;
        #pragma unroll
        for (int i = 0; i < 16; ++i) s += wc16[i];
        wsums_g[pt] = s;
    }
}

// =====================================================================
// K_B: 16 points per block, 512 threads (8 waves), 256 blocks.
// =====================================================================
__global__ __launch_bounds__(512) void kb_kernel(
    const __half* __restrict__ T,
    const float* __restrict__ Wp,      // [COUT, CIN] fp32
    const float* __restrict__ bp,      // [COUT]
    const float* __restrict__ wts_g,   // [4096][16]
    const int*   __restrict__ sites_g, // [4096][16]
    const float* __restrict__ wsums_g, // [4096]
    float* __restrict__ out)           // [4096, COUT]
{
    __shared__ float xsh[16][260];         // gathered X, padded rows
    __shared__ float wtile[32 * 256];      // Wp chunk [c][o-swizzled], 32 KB
    __shared__ float swts[16][16];
    __shared__ int   ssites[16][16];
    __shared__ float swsum[16];

    const int blk = blockIdx.x;            // 0..255
    const int p0g = blk << 4;              // first global point
    const int tid = threadIdx.x;

    if (tid < 256) {
        swts[tid >> 4][tid & 15]   = wts_g[p0g * 16 + tid];
        ssites[tid >> 4][tid & 15] = sites_g[p0g * 16 + tid];
    } else if (tid < 256 + 16) {
        swsum[tid - 256] = wsums_g[p0g + (tid - 256)];
    }
    __syncthreads();

    // ---- gather: thread owns (point p, channel octet oct) ----
    {
        const int p   = tid >> 5;          // 0..15
        const int oct = tid & 31;          // 0..31
        const int c0  = oct << 3;
        float a[8] = {0.f, 0.f, 0.f, 0.f, 0.f, 0.f, 0.f, 0.f};
        #pragma unroll
        for (int s = 0; s < 16; ++s) {
            const float w = swts[p][s];
            const uint4 raw = *reinterpret_cast<const uint4*>(T + (size_t)ssites[p][s] + c0);
            const __half* hh = reinterpret_cast<const __half*>(&raw);
            #pragma unroll
            for (int j = 0; j < 8; ++j)
                a[j] = fmaf(w, __half2float(hh[j]), a[j]);
        }
        *reinterpret_cast<float4*>(&xsh[p][c0])     = make_float4(a[0], a[1], a[2], a[3]);
        *reinterpret_cast<float4*>(&xsh[p][c0 + 4]) = make_float4(a[4], a[5], a[6], a[7]);
    }
    __syncthreads();

    // ---- matvec: thread owns 2 points x 4 outputs ----
    const int oq = tid & 63;               // o0 = oq*4
    const int pp = tid >> 6;               // wave id; p0 = pp*2
    const int o0 = oq << 2;
    const int p0 = pp << 1;

    const float4 bpv = *reinterpret_cast<const float4*>(bp + o0);
    const float ws0 = swsum[p0], ws1 = swsum[p0 + 1];
    float a00 = bpv.x * ws0, a01 = bpv.y * ws0, a02 = bpv.z * ws0, a03 = bpv.w * ws0;
    float a10 = bpv.x * ws1, a11 = bpv.y * ws1, a12 = bpv.z * ws1, a13 = bpv.w * ws1;

    for (int ch = 0; ch < 8; ++ch) {
        #pragma unroll
        for (int r = 0; r < 4; ++r) {
            const int idx = r * 512 + tid;     // 0..2047
            const int c4  = idx & 7;           // c-quad within chunk
            const int o   = idx >> 3;          // 0..255
            const float4 v = *reinterpret_cast<const float4*>(Wp + (size_t)o * CIN_ + ch * 32 + c4 * 4);
            const float vv[4] = {v.x, v.y, v.z, v.w};
            #pragma unroll
            for (int m = 0; m < 4; ++m) {
                const int c  = c4 * 4 + m;
                const int os = (o >> 2) ^ (c & 7);         // swizzled o-quad
                wtile[c * 256 + (os << 2) + (o & 3)] = vv[m];
            }
        }
        __syncthreads();

        const int cb = ch * 32;
        #pragma unroll
        for (int cq = 0; cq < 8; ++cq) {
            const float4 x0 = *reinterpret_cast<const float4*>(&xsh[p0][cb + (cq << 2)]);
            const float4 x1 = *reinterpret_cast<const float4*>(&xsh[p0 + 1][cb + (cq << 2)]);
            const float x0a[4] = {x0.x, x0.y, x0.z, x0.w};
            const float x1a[4] = {x1.x, x1.y, x1.z, x1.w};
            #pragma unroll
            for (int m = 0; m < 4; ++m) {
                const int c = (cq << 2) + m;
                const float4 wv = *reinterpret_cast<const float4*>(
                    &wtile[c * 256 + ((oq ^ (c & 7)) << 2)]);
                const float xm0 = x0a[m], xm1 = x1a[m];
                a00 = fmaf(xm0, wv.x, a00); a01 = fmaf(xm0, wv.y, a01);
                a02 = fmaf(xm0, wv.z, a02); a03 = fmaf(xm0, wv.w, a03);
                a10 = fmaf(xm1, wv.x, a10); a11 = fmaf(xm1, wv.y, a11);
                a12 = fmaf(xm1, wv.z, a12); a13 = fmaf(xm1, wv.w, a13);
            }
        }
        __syncthreads();
    }

    float* o_row0 = out + (size_t)(p0g + p0) * COUT_ + o0;
    float* o_row1 = out + (size_t)(p0g + p0 + 1) * COUT_ + o0;
    *reinterpret_cast<float4*>(o_row0) = make_float4(a00, a01, a02, a03);
    *reinterpret_cast<float4*>(o_row1) = make_float4(a10, a11, a12, a13);
}

// =====================================================================
// Fallback (round-1 kernel): used only if ws_size is too small.
// =====================================================================
__global__ __launch_bounds__(256) void ple_point_kernel(
    const float* __restrict__ input, const float* __restrict__ ax,
    const float* __restrict__ ay, const float* __restrict__ Wp,
    const float* __restrict__ bp, const float* __restrict__ Woff,
    const float* __restrict__ boff, const float* __restrict__ Ww,
    const float* __restrict__ bw, float* __restrict__ out)
{
    const int gid = blockIdx.x;
    const int b   = gid >> 9;
    const int tid = threadIdx.x;

    __shared__ float xs[CIN_];
    __shared__ float dotv[12];

    const int ix = (int)truncf(ax[gid]);
    const int iy = (int)truncf(ay[gid]);
    const float* __restrict__ chan = input + (size_t)b * (CIN_ * H_ * W_) + (size_t)tid * (H_ * W_);

    xs[tid] = chan[iy * W_ + ix];
    __syncthreads();

    const int wave = tid >> 6;
    const int lane = tid & 63;
    #pragma unroll
    for (int r = 0; r < 3; ++r) {
        const int d = wave * 3 + r;
        const float* __restrict__ row = (d < 8) ? (Woff + d * CIN_) : (Ww + (d - 8) * CIN_);
        float s = 0.f;
        #pragma unroll
        for (int q = 0; q < 4; ++q) s = fmaf(xs[lane + q * 64], row[lane + q * 64], s);
        #pragma unroll
        for (int off = 32; off > 0; off >>= 1) s += __shfl_down(s, off);
        if (lane == 0) dotv[d] = s;
    }
    __syncthreads();

    float lg[K_];
    float mx = -1e30f;
    #pragma unroll
    for (int k = 0; k < K_; ++k) { lg[k] = dotv[8 + k] + bw[k]; mx = fmaxf(mx, lg[k]); }
    float se = 0.f;
    #pragma unroll
    for (int k = 0; k < K_; ++k) { lg[k] = expf(lg[k] - mx); se += lg[k]; }
    const float inv_se = 1.f / se;
    const float scale = 128.0f / 127.0f;

    float xacc = 0.f, wsum = 0.f;
    #pragma unroll
    for (int k = 0; k < K_; ++k) {
        const float wk = lg[k] * inv_se;
        const float fx = dotv[2 * k] + boff[2 * k];
        const float fy = dotv[2 * k + 1] + boff[2 * k + 1];
        const float sxv = ((float)ix + fx) * scale - 0.5f;
        const float syv = ((float)iy + fy) * scale - 0.5f;
        const float x0f = floorf(sxv), y0f = floorf(syv);
        const float wx1 = sxv - x0f, wy1 = syv - y0f;
        const int x0 = (int)x0f, y0 = (int)y0f;
        const int x1 = x0 + 1, y1 = y0 + 1;
        const float w00 = (1.f - wx1) * (1.f - wy1) * wk;
        const float w10 = wx1 * (1.f - wy1) * wk;
        const float w01 = (1.f - wx1) * wy1 * wk;
        const float w11 = wx1 * wy1 * wk;
        const bool vx0 = (x0 >= 0) && (x0 < W_);
        const bool vx1 = (x1 >= 0) && (x1 < W_);
        if (y0 >= 0 && y0 < H_) {
            const float* rowp = chan + y0 * W_;
            if (vx0) { xacc = fmaf(w00, rowp[x0], xacc); wsum += w00; }
            if (vx1) { xacc = fmaf(w10, rowp[x1], xacc); wsum += w10; }
        }
        if (y1 >= 0 && y1 < H_) {
            const float* rowp = chan + y1 * W_;
            if (vx0) { xacc = fmaf(w01, rowp[x0], xacc); wsum += w01; }
            if (vx1) { xacc = fmaf(w11, rowp[x1], xacc); wsum += w11; }
        }
    }

    xs[tid] = xacc;
    __syncthreads();

    const float* __restrict__ wrow = Wp + tid * CIN_;
    float a0 = bp[tid] * wsum, a1 = 0.f, a2 = 0.f, a3 = 0.f;
    #pragma unroll 4
    for (int c = 0; c < CIN_; c += 4) {
        const float4 wv = *reinterpret_cast<const float4*>(wrow + c);
        a0 = fmaf(wv.x, xs[c], a0);
        a1 = fmaf(wv.y, xs[c + 1], a1);
        a2 = fmaf(wv.z, xs[c + 2], a2);
        a3 = fmaf(wv.w, xs[c + 3], a3);
    }
    out[(size_t)gid * COUT_ + tid] = (a0 + a1) + (a2 + a3);
}

extern "C" void kernel_launch(void* const* d_in, const int* in_sizes, int n_in,
                              void* d_out, int out_size, void* d_ws, size_t ws_size,
                              hipStream_t stream) {
    const float* input = (const float*)d_in[0];
    const float* ax    = (const float*)d_in[1];
    const float* ay    = (const float*)d_in[2];
    const float* Wp    = (const float*)d_in[3];
    const float* bp    = (const float*)d_in[4];
    const float* Woff  = (const float*)d_in[5];
    const float* boff  = (const float*)d_in[6];
    const float* Ww    = (const float*)d_in[7];
    const float* bw    = (const float*)d_in[8];
    float* out = (float*)d_out;

    if (ws_size >= WS_NEED_) {
        __half* T      = (__half*)d_ws;
        float*  wts_g  = (float*)((char*)d_ws + WTS_OFF_);
        int*    sites_g= (int*)  ((char*)d_ws + SITES_OFF_);
        float*  wsums_g= (float*)((char*)d_ws + WSUM_OFF_);

        ka_kernel<<<dim3(8192 + NPTS_TOT_), dim3(256), 0, stream>>>(
            input, ax, ay, Woff, boff, Ww, bw, T, wts_g, sites_g, wsums_g);
        kb_kernel<<<dim3(256), dim3(512), 0, stream>>>(
            T, Wp, bp, wts_g, sites_g, wsums_g, out);
    } else {
        ple_point_kernel<<<dim3(B_ * NPTS_), dim3(256), 0, stream>>>(
            input, ax, ay, Wp, bp, Woff, boff, Ww, bw, out);
    }
}